// Round 1
// baseline (467.180 us; speedup 1.0000x reference)
//
#include <hip/hip_runtime.h>
#include <hip/hip_bf16.h>

#define NPv 512
#define NCv 128
#define Ev  256
#define Cv  128

typedef __attribute__((ext_vector_type(4))) float f32x4;
typedef __attribute__((ext_vector_type(8))) short s16x8;

__device__ __forceinline__ unsigned short f2bf(float f) {
    union { float f; unsigned u; } v; v.f = f;
    unsigned r = v.u + 0x7fffu + ((v.u >> 16) & 1u);
    return (unsigned short)(r >> 16);
}
__device__ __forceinline__ float bf2f(unsigned short h) {
    union { unsigned u; float f; } v; v.u = ((unsigned)h) << 16;
    return v.f;
}
__device__ __forceinline__ float sigmoidf_(float x) {
    return 1.0f / (1.0f + __expf(-x));
}
__device__ __forceinline__ f32x4 mfma16(s16x8 a, s16x8 b, f32x4 c) {
    return __builtin_amdgcn_mfma_f32_16x16x32_bf16(a, b, c, 0, 0, 0);
}

// ---------------------------------------------------------------------------
// Weight prep: transpose all weight matrices to [n][k] bf16 (B^T, k-contig)
// layout in wts: gw1t(0) w1t(32768) gw2t(65536) w2t(98304) wet(131072) wst(196608)
// ---------------------------------------------------------------------------
__global__ void prep_weights(const float* __restrict__ gw1, const float* __restrict__ w1,
                             const float* __restrict__ gw2, const float* __restrict__ w2,
                             const float* __restrict__ we,  const float* __restrict__ wsm,
                             unsigned short* __restrict__ out)
{
    int bid = blockIdx.x, t = threadIdx.x;
    const float* src; int K, N; size_t doff; int lb = bid;
    if (lb < 512)      { int mi = lb >> 7; lb &= 127; K = 256; N = 128; doff = (size_t)mi * 32768;
                         src = (mi == 0) ? gw1 : (mi == 1) ? w1 : (mi == 2) ? gw2 : w2; }
    else if (lb < 768) { lb -= 512; K = 256; N = 256; doff = 131072; src = we; }
    else               { lb -= 768; K = 128; N = 256; doff = 196608; src = wsm; }
    int o = lb * 256 + t;
    int n = o / K, k = o % K;
    out[doff + o] = f2bf(src[(size_t)k * N + n]);
}

// ---------------------------------------------------------------------------
// LN over E=256 + gated projection(s). X:[M][256] f32. Outputs written as
// plain transposes outT[c][m] (bf16), g (if any) in natural [m][256] bf16.
// Workgroup: 256 threads = 4 waves, 64-row M-tile; wave tile 32m x 64n.
// ---------------------------------------------------------------------------
template<int HAS2, int HASG, int HASMASK>
__global__ __launch_bounds__(256, 2)
void ln_gate_kernel(const float* __restrict__ X, int M,
                    const float* __restrict__ lnw,
                    const unsigned short* __restrict__ Bu1, const unsigned short* __restrict__ Bv1,
                    const float* __restrict__ bias1, unsigned short* __restrict__ out1,
                    const unsigned short* __restrict__ Bu2, const unsigned short* __restrict__ Bv2,
                    const float* __restrict__ bias2, unsigned short* __restrict__ out2,
                    const unsigned short* __restrict__ Bwe, const float* __restrict__ be,
                    unsigned short* __restrict__ gout,
                    const float* __restrict__ mask)
{
    __shared__ unsigned short A_s[64][264];   // LN'd rows, bf16, padded
    __shared__ unsigned short T_s[128][80];   // transpose staging for outT
    const int t = threadIdx.x;
    const int lane = t & 63, w = t >> 6;
    const int l15 = lane & 15, lg = lane >> 4;
    const int m0 = blockIdx.x * 64;
    const int wy = w >> 1, wx = w & 1;

    // ---- LN phase: one wave per row, 16 rows per wave ----
    float4 lw = *reinterpret_cast<const float4*>(lnw + lane * 4);
    for (int r = w; r < 64; r += 4) {
        float4 x = *reinterpret_cast<const float4*>(X + (size_t)(m0 + r) * Ev + lane * 4);
        float s  = x.x + x.y + x.z + x.w;
        float s2 = x.x * x.x + x.y * x.y + x.z * x.z + x.w * x.w;
        for (int o = 1; o < 64; o <<= 1) { s += __shfl_xor(s, o); s2 += __shfl_xor(s2, o); }
        float mean = s * (1.0f / Ev);
        float var  = s2 * (1.0f / Ev) - mean * mean;
        float rstd = rsqrtf(var + 1e-5f);
        unsigned short* dst = &A_s[r][lane * 4];
        dst[0] = f2bf((x.x - mean) * rstd * lw.x);
        dst[1] = f2bf((x.y - mean) * rstd * lw.y);
        dst[2] = f2bf((x.z - mean) * rstd * lw.z);
        dst[3] = f2bf((x.w - mean) * rstd * lw.w);
    }
    __syncthreads();

    // ---- gated GEMM pass: u = X@Bu, v = X@Bv + bias; out = sig(u)*v [*mask] ----
    auto gated = [&](const unsigned short* Bu, const unsigned short* Bv,
                     const float* bias, unsigned short* outT) {
        f32x4 au[2][4] = {};
        f32x4 av[2][4] = {};
        for (int kk = 0; kk < Ev; kk += 32) {
            const int kc = kk + lg * 8;
            s16x8 a[2], bu[4], bv[4];
            #pragma unroll
            for (int fi = 0; fi < 2; fi++)
                a[fi] = *reinterpret_cast<const s16x8*>(&A_s[wy * 32 + fi * 16 + l15][kc]);
            #pragma unroll
            for (int fj = 0; fj < 4; fj++) {
                int n = wx * 64 + fj * 16 + l15;
                bu[fj] = *reinterpret_cast<const s16x8*>(Bu + (size_t)n * Ev + kc);
                bv[fj] = *reinterpret_cast<const s16x8*>(Bv + (size_t)n * Ev + kc);
            }
            #pragma unroll
            for (int fi = 0; fi < 2; fi++)
                #pragma unroll
                for (int fj = 0; fj < 4; fj++) {
                    au[fi][fj] = mfma16(a[fi], bu[fj], au[fi][fj]);
                    av[fi][fj] = mfma16(a[fi], bv[fj], av[fi][fj]);
                }
        }
        #pragma unroll
        for (int fi = 0; fi < 2; fi++)
            #pragma unroll
            for (int r = 0; r < 4; r++) {
                int ml = wy * 32 + fi * 16 + lg * 4 + r;
                float mval = HASMASK ? mask[m0 + ml] : 1.0f;
                #pragma unroll
                for (int fj = 0; fj < 4; fj++) {
                    int c = wx * 64 + fj * 16 + l15;
                    float val = sigmoidf_(au[fi][fj][r]) * (av[fi][fj][r] + bias[c]);
                    T_s[c][ml] = f2bf(val * mval);
                }
            }
        __syncthreads();
        #pragma unroll
        for (int it = 0; it < 4; it++) {
            int cid = it * 256 + t; int c = cid >> 3, ch = cid & 7;
            *reinterpret_cast<float4*>(outT + (size_t)c * M + m0 + ch * 8) =
                *reinterpret_cast<const float4*>(&T_s[c][ch * 8]);
        }
        __syncthreads();
    };

    gated(Bu1, Bv1, bias1, out1);
    if (HAS2) gated(Bu2, Bv2, bias2, out2);

    if (HASG) {
        #pragma unroll
        for (int half = 0; half < 2; half++) {
            f32x4 au[2][4] = {};
            for (int kk = 0; kk < Ev; kk += 32) {
                const int kc = kk + lg * 8;
                s16x8 a[2], bu[4];
                #pragma unroll
                for (int fi = 0; fi < 2; fi++)
                    a[fi] = *reinterpret_cast<const s16x8*>(&A_s[wy * 32 + fi * 16 + l15][kc]);
                #pragma unroll
                for (int fj = 0; fj < 4; fj++) {
                    int n = half * 128 + wx * 64 + fj * 16 + l15;
                    bu[fj] = *reinterpret_cast<const s16x8*>(Bwe + (size_t)n * Ev + kc);
                }
                #pragma unroll
                for (int fi = 0; fi < 2; fi++)
                    #pragma unroll
                    for (int fj = 0; fj < 4; fj++)
                        au[fi][fj] = mfma16(a[fi], bu[fj], au[fi][fj]);
            }
            #pragma unroll
            for (int fi = 0; fi < 2; fi++)
                #pragma unroll
                for (int fj = 0; fj < 4; fj++) {
                    int n = half * 128 + wx * 64 + fj * 16 + l15;
                    float bev = be[n];
                    #pragma unroll
                    for (int r = 0; r < 4; r++) {
                        int ml = wy * 32 + fi * 16 + lg * 4 + r;
                        gout[(size_t)(m0 + ml) * Ev + n] = f2bf(sigmoidf_(au[fi][fj][r] + bev));
                    }
                }
        }
    }
}

// ---------------------------------------------------------------------------
// ab1 transpose: [c][ip 512][jc 128] -> [c][jc 128][ip 512]
// ---------------------------------------------------------------------------
__global__ void transpose_ab1(const unsigned short* __restrict__ in,
                              unsigned short* __restrict__ out)
{
    __shared__ unsigned short T[64][72];
    const int t = threadIdx.x;
    const int c   = blockIdx.z;
    const int ip0 = blockIdx.x * 64;
    const int jc0 = blockIdx.y * 64;
    const unsigned short* src = in  + (size_t)c * (NPv * NCv);
    unsigned short*       dst = out + (size_t)c * (NPv * NCv);
    #pragma unroll
    for (int it = 0; it < 2; it++) {
        int cid = it * 256 + t; int r = cid >> 3, ch = cid & 7;
        *reinterpret_cast<float4*>(&T[r][ch * 8]) =
            *reinterpret_cast<const float4*>(src + (size_t)(ip0 + r) * NCv + jc0 + ch * 8);
    }
    __syncthreads();
    #pragma unroll
    for (int it = 0; it < 2; it++) {
        int cid = it * 256 + t; int jr = cid >> 3, ch = cid & 7;
        unsigned short v[8];
        #pragma unroll
        for (int e = 0; e < 8; e++) v[e] = T[ch * 8 + e][jr];
        *reinterpret_cast<float4*>(dst + (size_t)(jc0 + jr) * NPv + ip0 + ch * 8) =
            *reinterpret_cast<const float4*>(v);
    }
}

// ---------------------------------------------------------------------------
// block1 + block2 fused, per channel c: acc[i][j] = sum_k pp[c][i][k]*ab1tt[c][j][k]
//                                             + sum_k2 ab2t[c][i][k2]*cpt[c][j][k2]
// Workgroup: 4 waves, tile 128i x 128j, one c. Output blockT[c][i*128+j] f32.
// ---------------------------------------------------------------------------
__global__ __launch_bounds__(256, 2)
void block_kernel(const unsigned short* __restrict__ ppt,
                  const unsigned short* __restrict__ ab1tt,
                  const unsigned short* __restrict__ ab2t,
                  const unsigned short* __restrict__ cpt,
                  float* __restrict__ blockT)
{
    __shared__ unsigned short A_s[128][40];
    __shared__ unsigned short B_s[128][40];
    const int t = threadIdx.x, lane = t & 63, w = t >> 6;
    const int l15 = lane & 15, lg = lane >> 4;
    const int c  = blockIdx.x;
    const int i0 = blockIdx.y * 128;
    const int wy = w >> 1, wx = w & 1;
    f32x4 acc[4][4] = {};

    const unsigned short* pa = ppt   + (size_t)c * (NPv * NPv);  // [i][k] K=512
    const unsigned short* pb = ab1tt + (size_t)c * (NCv * NPv);  // [j][k] K=512
    for (int kk = 0; kk < NPv; kk += 32) {
        __syncthreads();
        #pragma unroll
        for (int it = 0; it < 2; it++) {
            int cid = it * 256 + t; int r = cid >> 2, ch = cid & 3;
            *reinterpret_cast<float4*>(&A_s[r][ch * 8]) =
                *reinterpret_cast<const float4*>(pa + (size_t)(i0 + r) * NPv + kk + ch * 8);
            *reinterpret_cast<float4*>(&B_s[r][ch * 8]) =
                *reinterpret_cast<const float4*>(pb + (size_t)r * NPv + kk + ch * 8);
        }
        __syncthreads();
        s16x8 a[4], b[4];
        #pragma unroll
        for (int f = 0; f < 4; f++) {
            a[f] = *reinterpret_cast<const s16x8*>(&A_s[wy * 64 + f * 16 + l15][lg * 8]);
            b[f] = *reinterpret_cast<const s16x8*>(&B_s[wx * 64 + f * 16 + l15][lg * 8]);
        }
        #pragma unroll
        for (int fi = 0; fi < 4; fi++)
            #pragma unroll
            for (int fj = 0; fj < 4; fj++)
                acc[fi][fj] = mfma16(a[fi], b[fj], acc[fi][fj]);
    }

    const unsigned short* pa2 = ab2t + (size_t)c * (NPv * NCv);  // [i][k2] K=128
    const unsigned short* pb2 = cpt  + (size_t)c * (NCv * NCv);  // [j][k2] K=128
    for (int kk = 0; kk < NCv; kk += 32) {
        __syncthreads();
        #pragma unroll
        for (int it = 0; it < 2; it++) {
            int cid = it * 256 + t; int r = cid >> 2, ch = cid & 3;
            *reinterpret_cast<float4*>(&A_s[r][ch * 8]) =
                *reinterpret_cast<const float4*>(pa2 + (size_t)(i0 + r) * NCv + kk + ch * 8);
            *reinterpret_cast<float4*>(&B_s[r][ch * 8]) =
                *reinterpret_cast<const float4*>(pb2 + (size_t)r * NCv + kk + ch * 8);
        }
        __syncthreads();
        s16x8 a[4], b[4];
        #pragma unroll
        for (int f = 0; f < 4; f++) {
            a[f] = *reinterpret_cast<const s16x8*>(&A_s[wy * 64 + f * 16 + l15][lg * 8]);
            b[f] = *reinterpret_cast<const s16x8*>(&B_s[wx * 64 + f * 16 + l15][lg * 8]);
        }
        #pragma unroll
        for (int fi = 0; fi < 4; fi++)
            #pragma unroll
            for (int fj = 0; fj < 4; fj++)
                acc[fi][fj] = mfma16(a[fi], b[fj], acc[fi][fj]);
    }

    float* dst = blockT + (size_t)c * (NPv * NCv);
    #pragma unroll
    for (int fi = 0; fi < 4; fi++)
        #pragma unroll
        for (int fj = 0; fj < 4; fj++) {
            int jc = wx * 64 + fj * 16 + l15;
            #pragma unroll
            for (int r = 0; r < 4; r++) {
                int il = wy * 64 + fi * 16 + lg * 4 + r;
                dst[(size_t)(i0 + il) * NCv + jc] = acc[fi][fj][r];
            }
        }
}

// ---------------------------------------------------------------------------
// Final: LN over c=128 of block (read from blockT[c][m]) -> @ws + bs, * g * mask
// Workgroup: 256 threads, 64-row M-tile; wave tile 32m x 128n.
// ---------------------------------------------------------------------------
__global__ __launch_bounds__(256, 2)
void final_kernel(const float* __restrict__ blockT,
                  const unsigned short* __restrict__ gbuf,
                  const unsigned short* __restrict__ wst,
                  const float* __restrict__ lncw,
                  const float* __restrict__ bs,
                  const float* __restrict__ mask,
                  float* __restrict__ out)
{
    __shared__ float Bl[128][68];
    __shared__ unsigned short A_s[64][136];
    __shared__ float red[8][64];
    const int t = threadIdx.x, lane = t & 63, w = t >> 6;
    const int l15 = lane & 15, lg = lane >> 4;
    const int m0 = blockIdx.x * 64;

    #pragma unroll
    for (int it = 0; it < 8; it++) {
        int cid = it * 256 + t; int c = cid >> 4, ch = cid & 15;
        *reinterpret_cast<float4*>(&Bl[c][ch * 4]) =
            *reinterpret_cast<const float4*>(blockT + (size_t)c * 65536 + m0 + ch * 4);
    }
    __syncthreads();

    const int m = t & 63, part = t >> 6;
    float s = 0.f, s2 = 0.f;
    for (int c = part * 32; c < part * 32 + 32; c++) { float v = Bl[c][m]; s += v; s2 += v * v; }
    red[part][m] = s; red[4 + part][m] = s2;
    __syncthreads();
    float ss  = red[0][m] + red[1][m] + red[2][m] + red[3][m];
    float ss2 = red[4][m] + red[5][m] + red[6][m] + red[7][m];
    float mean = ss * (1.0f / 128.0f);
    float var  = ss2 * (1.0f / 128.0f) - mean * mean;
    float rstd = rsqrtf(var + 1e-5f);
    for (int c = part * 32; c < part * 32 + 32; c++)
        A_s[m][c] = f2bf((Bl[c][m] - mean) * rstd * lncw[c]);
    __syncthreads();

    const int wy = w >> 1, wx = w & 1;
    f32x4 acc[2][8] = {};
    for (int kk = 0; kk < 128; kk += 32) {
        const int kc = kk + lg * 8;
        s16x8 a[2], b[8];
        #pragma unroll
        for (int fi = 0; fi < 2; fi++)
            a[fi] = *reinterpret_cast<const s16x8*>(&A_s[wy * 32 + fi * 16 + l15][kc]);
        #pragma unroll
        for (int fj = 0; fj < 8; fj++) {
            int n = wx * 128 + fj * 16 + l15;
            b[fj] = *reinterpret_cast<const s16x8*>(wst + (size_t)n * 128 + kc);
        }
        #pragma unroll
        for (int fi = 0; fi < 2; fi++)
            #pragma unroll
            for (int fj = 0; fj < 8; fj++)
                acc[fi][fj] = mfma16(a[fi], b[fj], acc[fi][fj]);
    }
    #pragma unroll
    for (int fi = 0; fi < 2; fi++)
        #pragma unroll
        for (int fj = 0; fj < 8; fj++) {
            int n = wx * 128 + fj * 16 + l15;
            float bsn = bs[n];
            #pragma unroll
            for (int r = 0; r < 4; r++) {
                int ml = wy * 32 + fi * 16 + lg * 4 + r;
                float gval = bf2f(gbuf[(size_t)(m0 + ml) * Ev + n]);
                out[(size_t)(m0 + ml) * Ev + n] =
                    gval * (acc[fi][fj][r] + bsn) * mask[m0 + ml];
            }
        }
}

// ---------------------------------------------------------------------------
extern "C" void kernel_launch(void* const* d_in, const int* in_sizes, int n_in,
                              void* d_out, int out_size, void* d_ws, size_t ws_size,
                              hipStream_t stream)
{
    const float* z    = (const float*)d_in[0];
    const float* ppin = (const float*)d_in[1];
    const float* cpin = (const float*)d_in[2];
    const float* mask = (const float*)d_in[3];
    const float* lnw  = (const float*)d_in[4];
    const float* lncw = (const float*)d_in[5];
    const float* gw1  = (const float*)d_in[6];
    const float* gw2  = (const float*)d_in[7];
    const float* w1   = (const float*)d_in[8];
    const float* b1   = (const float*)d_in[9];
    const float* w2   = (const float*)d_in[10];
    const float* b2   = (const float*)d_in[11];
    const float* we   = (const float*)d_in[12];
    const float* be   = (const float*)d_in[13];
    const float* wsm  = (const float*)d_in[14];
    const float* bs   = (const float*)d_in[15];
    float* out = (float*)d_out;

    char* p = (char*)d_ws;
    auto alloc = [&](size_t bytes) { char* r = p; p += (bytes + 255) & ~(size_t)255; return r; };
    unsigned short* wts    = (unsigned short*)alloc((size_t)229376 * 2);
    unsigned short* abt1   = (unsigned short*)alloc((size_t)128 * 65536 * 2);
    unsigned short* ab2t   = (unsigned short*)alloc((size_t)128 * 65536 * 2);
    unsigned short* ab1tt  = (unsigned short*)alloc((size_t)128 * 65536 * 2);
    unsigned short* pptb   = (unsigned short*)alloc((size_t)128 * 262144 * 2);
    unsigned short* cptb   = (unsigned short*)alloc((size_t)128 * 16384 * 2);
    unsigned short* gbuf   = (unsigned short*)alloc((size_t)65536 * 256 * 2);
    float*          blockT = (float*)alloc((size_t)128 * 65536 * 4);

    unsigned short* gw1t = wts + 0;
    unsigned short* w1t  = wts + 32768;
    unsigned short* gw2t = wts + 65536;
    unsigned short* w2t  = wts + 98304;
    unsigned short* wet  = wts + 131072;
    unsigned short* wst  = wts + 196608;

    hipLaunchKernelGGL(prep_weights, dim3(896), dim3(256), 0, stream,
                       gw1, w1, gw2, w2, we, wsm, wts);
    hipLaunchKernelGGL((ln_gate_kernel<1, 1, 1>), dim3(1024), dim3(256), 0, stream,
                       z, 65536, lnw, gw1t, w1t, b1, abt1, gw2t, w2t, b2, ab2t,
                       wet, be, gbuf, mask);
    hipLaunchKernelGGL((ln_gate_kernel<0, 0, 0>), dim3(4096), dim3(256), 0, stream,
                       ppin, 262144, lnw, gw2t, w2t, b2, pptb,
                       (const unsigned short*)nullptr, (const unsigned short*)nullptr,
                       (const float*)nullptr, (unsigned short*)nullptr,
                       (const unsigned short*)nullptr, (const float*)nullptr,
                       (unsigned short*)nullptr, (const float*)nullptr);
    hipLaunchKernelGGL((ln_gate_kernel<0, 0, 0>), dim3(256), dim3(256), 0, stream,
                       cpin, 16384, lnw, gw1t, w1t, b1, cptb,
                       (const unsigned short*)nullptr, (const unsigned short*)nullptr,
                       (const float*)nullptr, (unsigned short*)nullptr,
                       (const unsigned short*)nullptr, (const float*)nullptr,
                       (unsigned short*)nullptr, (const float*)nullptr);
    hipLaunchKernelGGL(transpose_ab1, dim3(8, 2, 128), dim3(256), 0, stream, abt1, ab1tt);
    hipLaunchKernelGGL(block_kernel, dim3(128, 4), dim3(256), 0, stream,
                       pptb, ab1tt, ab2t, cptb, blockT);
    hipLaunchKernelGGL(final_kernel, dim3(1024), dim3(256), 0, stream,
                       blockT, gbuf, wst, lncw, bs, mask, out);
}

// Round 2
// 383.750 us; speedup vs baseline: 1.2174x; 1.2174x over previous
//
#include <hip/hip_runtime.h>
#include <hip/hip_bf16.h>

#define NPv 512
#define NCv 128
#define Ev  256
#define Cv  128

typedef __attribute__((ext_vector_type(4))) float f32x4;
typedef __attribute__((ext_vector_type(8))) short s16x8;

__device__ __forceinline__ unsigned short f2bf(float f) {
    union { float f; unsigned u; } v; v.f = f;
    unsigned r = v.u + 0x7fffu + ((v.u >> 16) & 1u);
    return (unsigned short)(r >> 16);
}
__device__ __forceinline__ float bf2f(unsigned short h) {
    union { unsigned u; float f; } v; v.u = ((unsigned)h) << 16;
    return v.f;
}
__device__ __forceinline__ float sigmoidf_(float x) {
    return 1.0f / (1.0f + __expf(-x));
}
__device__ __forceinline__ f32x4 mfma16(s16x8 a, s16x8 b, f32x4 c) {
    return __builtin_amdgcn_mfma_f32_16x16x32_bf16(a, b, c, 0, 0, 0);
}

// ---------------------------------------------------------------------------
// Weight prep: transpose all weight matrices to [n][k] bf16 (B^T, k-contig)
// ---------------------------------------------------------------------------
__global__ void prep_weights(const float* __restrict__ gw1, const float* __restrict__ w1,
                             const float* __restrict__ gw2, const float* __restrict__ w2,
                             const float* __restrict__ we,  const float* __restrict__ wsm,
                             unsigned short* __restrict__ out)
{
    int bid = blockIdx.x, t = threadIdx.x;
    const float* src; int K, N; size_t doff; int lb = bid;
    if (lb < 512)      { int mi = lb >> 7; lb &= 127; K = 256; N = 128; doff = (size_t)mi * 32768;
                         src = (mi == 0) ? gw1 : (mi == 1) ? w1 : (mi == 2) ? gw2 : w2; }
    else if (lb < 768) { lb -= 512; K = 256; N = 256; doff = 131072; src = we; }
    else               { lb -= 768; K = 128; N = 256; doff = 196608; src = wsm; }
    int o = lb * 256 + t;
    int n = o / K, k = o % K;
    out[doff + o] = f2bf(src[(size_t)k * N + n]);
}

// ---------------------------------------------------------------------------
// LN over E=256 + gated projection(s). X:[M][256] f32. Outputs written as
// plain transposes outT[c][m] (bf16), g (if any) in natural [m][256] bf16.
// Workgroup: 256 threads = 4 waves, 64-row M-tile; wave tile 32m x 64n.
// LN: 16-lane groups, 4 rows/wave/iter, lane owns 16 contiguous elements.
// ---------------------------------------------------------------------------
template<int HAS2, int HASG, int HASMASK>
__global__ __launch_bounds__(256, 3)
void ln_gate_kernel(const float* __restrict__ X, int M,
                    const float* __restrict__ lnw,
                    const unsigned short* __restrict__ Bu1, const unsigned short* __restrict__ Bv1,
                    const float* __restrict__ bias1, unsigned short* __restrict__ out1,
                    const unsigned short* __restrict__ Bu2, const unsigned short* __restrict__ Bv2,
                    const float* __restrict__ bias2, unsigned short* __restrict__ out2,
                    const unsigned short* __restrict__ Bwe, const float* __restrict__ be,
                    unsigned short* __restrict__ gout,
                    const float* __restrict__ mask)
{
    // A_s: 64 x 264 bf16 = 33792 B.  T_s: 128 x 72 bf16 = 18432 B.
    // For HAS2==0 (single gated pass), T_s overlays A_s (A_s dead by then).
    __shared__ __align__(16) char smem[HAS2 ? (33792 + 18432) : 33792];
    unsigned short (*A_s)[264] = reinterpret_cast<unsigned short(*)[264]>(smem);
    unsigned short (*T_s)[72]  = reinterpret_cast<unsigned short(*)[72]>(
                                     smem + (HAS2 ? 33792 : 0));
    const int t = threadIdx.x;
    const int lane = t & 63, w = t >> 6;
    const int l15 = lane & 15, lg = lane >> 4;
    const int m0 = blockIdx.x * 64;
    const int wy = w >> 1, wx = w & 1;

    // ---- LN phase: 4 rows per wave per iter; lane owns cols [l15*16, l15*16+16) ----
    float4 lwv[4];
    #pragma unroll
    for (int q = 0; q < 4; q++)
        lwv[q] = *reinterpret_cast<const float4*>(lnw + l15 * 16 + q * 4);
    #pragma unroll
    for (int i = 0; i < 4; i++) {
        const int r = w * 16 + i * 4 + lg;
        const float* xp = X + (size_t)(m0 + r) * Ev + l15 * 16;
        float4 xv[4];
        #pragma unroll
        for (int q = 0; q < 4; q++) xv[q] = *reinterpret_cast<const float4*>(xp + q * 4);
        float s = 0.f, s2 = 0.f;
        #pragma unroll
        for (int q = 0; q < 4; q++) {
            s  += xv[q].x + xv[q].y + xv[q].z + xv[q].w;
            s2 += xv[q].x * xv[q].x + xv[q].y * xv[q].y
                + xv[q].z * xv[q].z + xv[q].w * xv[q].w;
        }
        #pragma unroll
        for (int o = 1; o < 16; o <<= 1) { s += __shfl_xor(s, o); s2 += __shfl_xor(s2, o); }
        float mean = s * (1.0f / Ev);
        float var  = s2 * (1.0f / Ev) - mean * mean;
        float rstd = rsqrtf(var + 1e-5f);
        s16x8 o0, o1;
        #pragma unroll
        for (int q = 0; q < 4; q++) {
            float vx = (xv[q].x - mean) * rstd * lwv[q].x;
            float vy = (xv[q].y - mean) * rstd * lwv[q].y;
            float vz = (xv[q].z - mean) * rstd * lwv[q].z;
            float vw = (xv[q].w - mean) * rstd * lwv[q].w;
            if (q < 2) {
                o0[q * 4 + 0] = (short)f2bf(vx); o0[q * 4 + 1] = (short)f2bf(vy);
                o0[q * 4 + 2] = (short)f2bf(vz); o0[q * 4 + 3] = (short)f2bf(vw);
            } else {
                o1[(q - 2) * 4 + 0] = (short)f2bf(vx); o1[(q - 2) * 4 + 1] = (short)f2bf(vy);
                o1[(q - 2) * 4 + 2] = (short)f2bf(vz); o1[(q - 2) * 4 + 3] = (short)f2bf(vw);
            }
        }
        *reinterpret_cast<s16x8*>(&A_s[r][l15 * 16])     = o0;
        *reinterpret_cast<s16x8*>(&A_s[r][l15 * 16 + 8]) = o1;
    }
    __syncthreads();

    // ---- gated GEMM pass: u = X@Bu, v = X@Bv + bias; out = sig(u)*v [*mask] ----
    auto gated = [&](const unsigned short* Bu, const unsigned short* Bv,
                     const float* bias, unsigned short* outT) {
        f32x4 au[2][4] = {};
        f32x4 av[2][4] = {};
        for (int kk = 0; kk < Ev; kk += 32) {
            const int kc = kk + lg * 8;
            s16x8 a[2], bu[4], bv[4];
            #pragma unroll
            for (int fi = 0; fi < 2; fi++)
                a[fi] = *reinterpret_cast<const s16x8*>(&A_s[wy * 32 + fi * 16 + l15][kc]);
            #pragma unroll
            for (int fj = 0; fj < 4; fj++) {
                int n = wx * 64 + fj * 16 + l15;
                bu[fj] = *reinterpret_cast<const s16x8*>(Bu + (size_t)n * Ev + kc);
                bv[fj] = *reinterpret_cast<const s16x8*>(Bv + (size_t)n * Ev + kc);
            }
            #pragma unroll
            for (int fi = 0; fi < 2; fi++)
                #pragma unroll
                for (int fj = 0; fj < 4; fj++) {
                    au[fi][fj] = mfma16(a[fi], bu[fj], au[fi][fj]);
                    av[fi][fj] = mfma16(a[fi], bv[fj], av[fi][fj]);
                }
        }
        __syncthreads();   // all waves done reading A_s (T_s may overlay it)
        #pragma unroll
        for (int fi = 0; fi < 2; fi++)
            #pragma unroll
            for (int r = 0; r < 4; r++) {
                int ml = wy * 32 + fi * 16 + lg * 4 + r;
                float mval = HASMASK ? mask[m0 + ml] : 1.0f;
                #pragma unroll
                for (int fj = 0; fj < 4; fj++) {
                    int c = wx * 64 + fj * 16 + l15;
                    float val = sigmoidf_(au[fi][fj][r]) * (av[fi][fj][r] + bias[c]);
                    T_s[c][ml] = f2bf(val * mval);
                }
            }
        __syncthreads();
        #pragma unroll
        for (int it = 0; it < 4; it++) {
            int cid = it * 256 + t; int c = cid >> 3, ch = cid & 7;
            *reinterpret_cast<float4*>(outT + (size_t)c * M + m0 + ch * 8) =
                *reinterpret_cast<const float4*>(&T_s[c][ch * 8]);
        }
        __syncthreads();
    };

    gated(Bu1, Bv1, bias1, out1);
    if (HAS2) gated(Bu2, Bv2, bias2, out2);

    if (HASG) {
        unsigned short (*T2g)[144] = reinterpret_cast<unsigned short(*)[144]>(
                                         smem + (HAS2 ? 33792 : 0));
        #pragma unroll
        for (int half = 0; half < 2; half++) {
            f32x4 au[2][4] = {};
            for (int kk = 0; kk < Ev; kk += 32) {
                const int kc = kk + lg * 8;
                s16x8 a[2], bu[4];
                #pragma unroll
                for (int fi = 0; fi < 2; fi++)
                    a[fi] = *reinterpret_cast<const s16x8*>(&A_s[wy * 32 + fi * 16 + l15][kc]);
                #pragma unroll
                for (int fj = 0; fj < 4; fj++) {
                    int n = half * 128 + wx * 64 + fj * 16 + l15;
                    bu[fj] = *reinterpret_cast<const s16x8*>(Bwe + (size_t)n * Ev + kc);
                }
                #pragma unroll
                for (int fi = 0; fi < 2; fi++)
                    #pragma unroll
                    for (int fj = 0; fj < 4; fj++)
                        au[fi][fj] = mfma16(a[fi], bu[fj], au[fi][fj]);
            }
            __syncthreads();   // T2g overlays T_s; previous reads must complete
            #pragma unroll
            for (int fi = 0; fi < 2; fi++)
                #pragma unroll
                for (int fj = 0; fj < 4; fj++) {
                    int np = wx * 64 + fj * 16 + l15;
                    float bev = be[half * 128 + np];
                    #pragma unroll
                    for (int r = 0; r < 4; r++) {
                        int ml = wy * 32 + fi * 16 + lg * 4 + r;
                        T2g[ml][np] = f2bf(sigmoidf_(au[fi][fj][r] + bev));
                    }
                }
            __syncthreads();
            #pragma unroll
            for (int it = 0; it < 4; it++) {
                int cid = it * 256 + t; int m = cid >> 4, ch = cid & 15;
                *reinterpret_cast<float4*>(gout + (size_t)(m0 + m) * Ev + half * 128 + ch * 8) =
                    *reinterpret_cast<const float4*>(&T2g[m][ch * 8]);
            }
            __syncthreads();
        }
    }
}

// ---------------------------------------------------------------------------
// ab1 transpose: [c][ip 512][jc 128] -> [c][jc 128][ip 512]
// ---------------------------------------------------------------------------
__global__ void transpose_ab1(const unsigned short* __restrict__ in,
                              unsigned short* __restrict__ out)
{
    __shared__ unsigned short T[64][72];
    const int t = threadIdx.x;
    const int c   = blockIdx.z;
    const int ip0 = blockIdx.x * 64;
    const int jc0 = blockIdx.y * 64;
    const unsigned short* src = in  + (size_t)c * (NPv * NCv);
    unsigned short*       dst = out + (size_t)c * (NPv * NCv);
    #pragma unroll
    for (int it = 0; it < 2; it++) {
        int cid = it * 256 + t; int r = cid >> 3, ch = cid & 7;
        *reinterpret_cast<float4*>(&T[r][ch * 8]) =
            *reinterpret_cast<const float4*>(src + (size_t)(ip0 + r) * NCv + jc0 + ch * 8);
    }
    __syncthreads();
    #pragma unroll
    for (int it = 0; it < 2; it++) {
        int cid = it * 256 + t; int jr = cid >> 3, ch = cid & 7;
        unsigned short v[8];
        #pragma unroll
        for (int e = 0; e < 8; e++) v[e] = T[ch * 8 + e][jr];
        *reinterpret_cast<float4*>(dst + (size_t)(jc0 + jr) * NPv + ip0 + ch * 8) =
            *reinterpret_cast<const float4*>(v);
    }
}

// ---------------------------------------------------------------------------
// block1 + block2 fused, per channel c: acc[i][j] = sum_k pp[c][i][k]*ab1tt[c][j][k]
//                                             + sum_k2 ab2t[c][i][k2]*cpt[c][j][k2]
// ---------------------------------------------------------------------------
__global__ __launch_bounds__(256, 2)
void block_kernel(const unsigned short* __restrict__ ppt,
                  const unsigned short* __restrict__ ab1tt,
                  const unsigned short* __restrict__ ab2t,
                  const unsigned short* __restrict__ cpt,
                  float* __restrict__ blockT)
{
    __shared__ unsigned short A_s[128][40];
    __shared__ unsigned short B_s[128][40];
    const int t = threadIdx.x, lane = t & 63, w = t >> 6;
    const int l15 = lane & 15, lg = lane >> 4;
    const int c  = blockIdx.x;
    const int i0 = blockIdx.y * 128;
    const int wy = w >> 1, wx = w & 1;
    f32x4 acc[4][4] = {};

    const unsigned short* pa = ppt   + (size_t)c * (NPv * NPv);  // [i][k] K=512
    const unsigned short* pb = ab1tt + (size_t)c * (NCv * NPv);  // [j][k] K=512
    for (int kk = 0; kk < NPv; kk += 32) {
        __syncthreads();
        #pragma unroll
        for (int it = 0; it < 2; it++) {
            int cid = it * 256 + t; int r = cid >> 2, ch = cid & 3;
            *reinterpret_cast<float4*>(&A_s[r][ch * 8]) =
                *reinterpret_cast<const float4*>(pa + (size_t)(i0 + r) * NPv + kk + ch * 8);
            *reinterpret_cast<float4*>(&B_s[r][ch * 8]) =
                *reinterpret_cast<const float4*>(pb + (size_t)r * NPv + kk + ch * 8);
        }
        __syncthreads();
        s16x8 a[4], b[4];
        #pragma unroll
        for (int f = 0; f < 4; f++) {
            a[f] = *reinterpret_cast<const s16x8*>(&A_s[wy * 64 + f * 16 + l15][lg * 8]);
            b[f] = *reinterpret_cast<const s16x8*>(&B_s[wx * 64 + f * 16 + l15][lg * 8]);
        }
        #pragma unroll
        for (int fi = 0; fi < 4; fi++)
            #pragma unroll
            for (int fj = 0; fj < 4; fj++)
                acc[fi][fj] = mfma16(a[fi], b[fj], acc[fi][fj]);
    }

    const unsigned short* pa2 = ab2t + (size_t)c * (NPv * NCv);  // [i][k2] K=128
    const unsigned short* pb2 = cpt  + (size_t)c * (NCv * NCv);  // [j][k2] K=128
    for (int kk = 0; kk < NCv; kk += 32) {
        __syncthreads();
        #pragma unroll
        for (int it = 0; it < 2; it++) {
            int cid = it * 256 + t; int r = cid >> 2, ch = cid & 3;
            *reinterpret_cast<float4*>(&A_s[r][ch * 8]) =
                *reinterpret_cast<const float4*>(pa2 + (size_t)(i0 + r) * NCv + kk + ch * 8);
            *reinterpret_cast<float4*>(&B_s[r][ch * 8]) =
                *reinterpret_cast<const float4*>(pb2 + (size_t)r * NCv + kk + ch * 8);
        }
        __syncthreads();
        s16x8 a[4], b[4];
        #pragma unroll
        for (int f = 0; f < 4; f++) {
            a[f] = *reinterpret_cast<const s16x8*>(&A_s[wy * 64 + f * 16 + l15][lg * 8]);
            b[f] = *reinterpret_cast<const s16x8*>(&B_s[wx * 64 + f * 16 + l15][lg * 8]);
        }
        #pragma unroll
        for (int fi = 0; fi < 4; fi++)
            #pragma unroll
            for (int fj = 0; fj < 4; fj++)
                acc[fi][fj] = mfma16(a[fi], b[fj], acc[fi][fj]);
    }

    float* dst = blockT + (size_t)c * (NPv * NCv);
    #pragma unroll
    for (int fi = 0; fi < 4; fi++)
        #pragma unroll
        for (int fj = 0; fj < 4; fj++) {
            int jc = wx * 64 + fj * 16 + l15;
            #pragma unroll
            for (int r = 0; r < 4; r++) {
                int il = wy * 64 + fi * 16 + lg * 4 + r;
                dst[(size_t)(i0 + il) * NCv + jc] = acc[fi][fj][r];
            }
        }
}

// ---------------------------------------------------------------------------
// Final: LN over c=128 of block (read from blockT[c][m]) -> @ws + bs, * g * mask
// ---------------------------------------------------------------------------
__global__ __launch_bounds__(256, 2)
void final_kernel(const float* __restrict__ blockT,
                  const unsigned short* __restrict__ gbuf,
                  const unsigned short* __restrict__ wst,
                  const float* __restrict__ lncw,
                  const float* __restrict__ bs,
                  const float* __restrict__ mask,
                  float* __restrict__ out)
{
    __shared__ float Bl[128][68];
    __shared__ unsigned short A_s[64][136];
    __shared__ float red[8][64];
    const int t = threadIdx.x, lane = t & 63, w = t >> 6;
    const int l15 = lane & 15, lg = lane >> 4;
    const int m0 = blockIdx.x * 64;

    #pragma unroll
    for (int it = 0; it < 8; it++) {
        int cid = it * 256 + t; int c = cid >> 4, ch = cid & 15;
        *reinterpret_cast<float4*>(&Bl[c][ch * 4]) =
            *reinterpret_cast<const float4*>(blockT + (size_t)c * 65536 + m0 + ch * 4);
    }
    __syncthreads();

    const int m = t & 63, part = t >> 6;
    float s = 0.f, s2 = 0.f;
    for (int c = part * 32; c < part * 32 + 32; c++) { float v = Bl[c][m]; s += v; s2 += v * v; }
    red[part][m] = s; red[4 + part][m] = s2;
    __syncthreads();
    float ss  = red[0][m] + red[1][m] + red[2][m] + red[3][m];
    float ss2 = red[4][m] + red[5][m] + red[6][m] + red[7][m];
    float mean = ss * (1.0f / 128.0f);
    float var  = ss2 * (1.0f / 128.0f) - mean * mean;
    float rstd = rsqrtf(var + 1e-5f);
    for (int c = part * 32; c < part * 32 + 32; c++)
        A_s[m][c] = f2bf((Bl[c][m] - mean) * rstd * lncw[c]);
    __syncthreads();

    const int wy = w >> 1, wx = w & 1;
    f32x4 acc[2][8] = {};
    for (int kk = 0; kk < 128; kk += 32) {
        const int kc = kk + lg * 8;
        s16x8 a[2], b[8];
        #pragma unroll
        for (int fi = 0; fi < 2; fi++)
            a[fi] = *reinterpret_cast<const s16x8*>(&A_s[wy * 32 + fi * 16 + l15][kc]);
        #pragma unroll
        for (int fj = 0; fj < 8; fj++) {
            int n = wx * 128 + fj * 16 + l15;
            b[fj] = *reinterpret_cast<const s16x8*>(wst + (size_t)n * 128 + kc);
        }
        #pragma unroll
        for (int fi = 0; fi < 2; fi++)
            #pragma unroll
            for (int fj = 0; fj < 8; fj++)
                acc[fi][fj] = mfma16(a[fi], b[fj], acc[fi][fj]);
    }
    #pragma unroll
    for (int fi = 0; fi < 2; fi++)
        #pragma unroll
        for (int fj = 0; fj < 8; fj++) {
            int n = wx * 128 + fj * 16 + l15;
            float bsn = bs[n];
            #pragma unroll
            for (int r = 0; r < 4; r++) {
                int ml = wy * 32 + fi * 16 + lg * 4 + r;
                float gval = bf2f(gbuf[(size_t)(m0 + ml) * Ev + n]);
                out[(size_t)(m0 + ml) * Ev + n] =
                    gval * (acc[fi][fj][r] + bsn) * mask[m0 + ml];
            }
        }
}

// ---------------------------------------------------------------------------
extern "C" void kernel_launch(void* const* d_in, const int* in_sizes, int n_in,
                              void* d_out, int out_size, void* d_ws, size_t ws_size,
                              hipStream_t stream)
{
    const float* z    = (const float*)d_in[0];
    const float* ppin = (const float*)d_in[1];
    const float* cpin = (const float*)d_in[2];
    const float* mask = (const float*)d_in[3];
    const float* lnw  = (const float*)d_in[4];
    const float* lncw = (const float*)d_in[5];
    const float* gw1  = (const float*)d_in[6];
    const float* gw2  = (const float*)d_in[7];
    const float* w1   = (const float*)d_in[8];
    const float* b1   = (const float*)d_in[9];
    const float* w2   = (const float*)d_in[10];
    const float* b2   = (const float*)d_in[11];
    const float* we   = (const float*)d_in[12];
    const float* be   = (const float*)d_in[13];
    const float* wsm  = (const float*)d_in[14];
    const float* bs   = (const float*)d_in[15];
    float* out = (float*)d_out;

    char* p = (char*)d_ws;
    auto alloc = [&](size_t bytes) { char* r = p; p += (bytes + 255) & ~(size_t)255; return r; };
    unsigned short* wts    = (unsigned short*)alloc((size_t)229376 * 2);
    unsigned short* abt1   = (unsigned short*)alloc((size_t)128 * 65536 * 2);
    unsigned short* ab2t   = (unsigned short*)alloc((size_t)128 * 65536 * 2);
    unsigned short* ab1tt  = (unsigned short*)alloc((size_t)128 * 65536 * 2);
    unsigned short* pptb   = (unsigned short*)alloc((size_t)128 * 262144 * 2);
    unsigned short* cptb   = (unsigned short*)alloc((size_t)128 * 16384 * 2);
    unsigned short* gbuf   = (unsigned short*)alloc((size_t)65536 * 256 * 2);
    float*          blockT = (float*)alloc((size_t)128 * 65536 * 4);

    unsigned short* gw1t = wts + 0;
    unsigned short* w1t  = wts + 32768;
    unsigned short* gw2t = wts + 65536;
    unsigned short* w2t  = wts + 98304;
    unsigned short* wet  = wts + 131072;
    unsigned short* wst  = wts + 196608;

    hipLaunchKernelGGL(prep_weights, dim3(896), dim3(256), 0, stream,
                       gw1, w1, gw2, w2, we, wsm, wts);
    hipLaunchKernelGGL((ln_gate_kernel<1, 1, 1>), dim3(1024), dim3(256), 0, stream,
                       z, 65536, lnw, gw1t, w1t, b1, abt1, gw2t, w2t, b2, ab2t,
                       wet, be, gbuf, mask);
    hipLaunchKernelGGL((ln_gate_kernel<0, 0, 0>), dim3(4096), dim3(256), 0, stream,
                       ppin, 262144, lnw, gw2t, w2t, b2, pptb,
                       (const unsigned short*)nullptr, (const unsigned short*)nullptr,
                       (const float*)nullptr, (unsigned short*)nullptr,
                       (const unsigned short*)nullptr, (const float*)nullptr,
                       (unsigned short*)nullptr, (const float*)nullptr);
    hipLaunchKernelGGL((ln_gate_kernel<0, 0, 0>), dim3(256), dim3(256), 0, stream,
                       cpin, 16384, lnw, gw1t, w1t, b1, cptb,
                       (const unsigned short*)nullptr, (const unsigned short*)nullptr,
                       (const float*)nullptr, (unsigned short*)nullptr,
                       (const unsigned short*)nullptr, (const float*)nullptr,
                       (unsigned short*)nullptr, (const float*)nullptr);
    hipLaunchKernelGGL(transpose_ab1, dim3(8, 2, 128), dim3(256), 0, stream, abt1, ab1tt);
    hipLaunchKernelGGL(block_kernel, dim3(128, 4), dim3(256), 0, stream,
                       pptb, ab1tt, ab2t, cptb, blockT);
    hipLaunchKernelGGL(final_kernel, dim3(1024), dim3(256), 0, stream,
                       blockT, gbuf, wst, lncw, bs, mask, out);
}

// Round 3
// 257.116 us; speedup vs baseline: 1.8170x; 1.4925x over previous
//
#include <hip/hip_runtime.h>
#include <hip/hip_bf16.h>

#define NPv 512
#define NCv 128
#define Ev  256
#define Cv  128

typedef __attribute__((ext_vector_type(4))) float f32x4;
typedef __attribute__((ext_vector_type(8))) short s16x8;

__device__ __forceinline__ unsigned short f2bf(float f) {
    union { float f; unsigned u; } v; v.f = f;
    unsigned r = v.u + 0x7fffu + ((v.u >> 16) & 1u);
    return (unsigned short)(r >> 16);
}
__device__ __forceinline__ float bf2f(unsigned short h) {
    union { unsigned u; float f; } v; v.u = ((unsigned)h) << 16;
    return v.f;
}
__device__ __forceinline__ float sigmoidf_(float x) {
    return 1.0f / (1.0f + __expf(-x));
}
__device__ __forceinline__ f32x4 mfma16(s16x8 a, s16x8 b, f32x4 c) {
    return __builtin_amdgcn_mfma_f32_16x16x32_bf16(a, b, c, 0, 0, 0);
}

// ---------------------------------------------------------------------------
// Weight prep -> FRAG-MAJOR layout so B-fragment loads are lane-linear:
//   addr(n,k) = ((nb*KC + kc)*64 + lane)*8 + e
//   nb = n>>4, kc = k>>5, lane = (n&15) + 16*((k>>3)&3), e = k&7
// A wave's B-frag load for (nb,kc) is then base + lane*16B — fully coalesced.
// Offsets (halfwords): gw1t 0, w1t 32768, gw2t 65536, w2t 98304,
//                      wet 131072, wst 196608.
// ---------------------------------------------------------------------------
__global__ void prep_weights(const float* __restrict__ gw1, const float* __restrict__ w1,
                             const float* __restrict__ gw2, const float* __restrict__ w2,
                             const float* __restrict__ we,  const float* __restrict__ wsm,
                             unsigned short* __restrict__ out)
{
    int o = blockIdx.x * 256 + threadIdx.x;     // 0..229375
    const float* src; int N, KC; size_t base; int lo;
    if (o < 131072)      { int mi = o >> 15; lo = o & 32767; N = 128; KC = 8;
                           base = (size_t)mi * 32768;
                           src = (mi == 0) ? gw1 : (mi == 1) ? w1 : (mi == 2) ? gw2 : w2; }
    else if (o < 196608) { lo = o - 131072; N = 256; KC = 8; base = 131072; src = we; }
    else                 { lo = o - 196608; N = 256; KC = 4; base = 196608; src = wsm; }
    int e    = lo & 7;
    int lane = (lo >> 3) & 63;
    int blk  = lo >> 9;
    int kc   = blk % KC, nb = blk / KC;
    int n = nb * 16 + (lane & 15);
    int k = kc * 32 + ((lane >> 4) << 3) + e;
    out[base + lo] = f2bf(src[(size_t)k * N + n]);
}

// ---------------------------------------------------------------------------
// LN over E=256 + gated projection(s). X:[M][256] f32. Outputs written as
// plain transposes outT[c][m] (bf16), g (if any) in natural [m][256] bf16.
// B-fragments come from frag-major weights (coalesced lane-linear loads).
// ---------------------------------------------------------------------------
template<int HAS2, int HASG, int HASMASK>
__global__ __launch_bounds__(256, HAS2 ? 3 : 4)
void ln_gate_kernel(const float* __restrict__ X, int M,
                    const float* __restrict__ lnw,
                    const unsigned short* __restrict__ Bu1, const unsigned short* __restrict__ Bv1,
                    const float* __restrict__ bias1, unsigned short* __restrict__ out1,
                    const unsigned short* __restrict__ Bu2, const unsigned short* __restrict__ Bv2,
                    const float* __restrict__ bias2, unsigned short* __restrict__ out2,
                    const unsigned short* __restrict__ Bwe, const float* __restrict__ be,
                    unsigned short* __restrict__ gout,
                    const float* __restrict__ mask)
{
    // A_s: 64 x 264 bf16 = 33792 B.  T_s: 128 x 72 bf16 = 18432 B.
    // For HAS2==0 (single gated pass), T_s overlays A_s (A_s dead by then).
    __shared__ __align__(16) char smem[HAS2 ? (33792 + 18432) : 33792];
    unsigned short (*A_s)[264] = reinterpret_cast<unsigned short(*)[264]>(smem);
    unsigned short (*T_s)[72]  = reinterpret_cast<unsigned short(*)[72]>(
                                     smem + (HAS2 ? 33792 : 0));
    const int t = threadIdx.x;
    const int lane = t & 63, w = t >> 6;
    const int l15 = lane & 15, lg = lane >> 4;
    const int m0 = blockIdx.x * 64;
    const int wy = w >> 1, wx = w & 1;

    // ---- LN phase: 4 rows per wave per iter; lane owns cols [l15*16, l15*16+16) ----
    float4 lwv[4];
    #pragma unroll
    for (int q = 0; q < 4; q++)
        lwv[q] = *reinterpret_cast<const float4*>(lnw + l15 * 16 + q * 4);
    #pragma unroll
    for (int i = 0; i < 4; i++) {
        const int r = w * 16 + i * 4 + lg;
        const float* xp = X + (size_t)(m0 + r) * Ev + l15 * 16;
        float4 xv[4];
        #pragma unroll
        for (int q = 0; q < 4; q++) xv[q] = *reinterpret_cast<const float4*>(xp + q * 4);
        float s = 0.f, s2 = 0.f;
        #pragma unroll
        for (int q = 0; q < 4; q++) {
            s  += xv[q].x + xv[q].y + xv[q].z + xv[q].w;
            s2 += xv[q].x * xv[q].x + xv[q].y * xv[q].y
                + xv[q].z * xv[q].z + xv[q].w * xv[q].w;
        }
        #pragma unroll
        for (int o = 1; o < 16; o <<= 1) { s += __shfl_xor(s, o); s2 += __shfl_xor(s2, o); }
        float mean = s * (1.0f / Ev);
        float var  = s2 * (1.0f / Ev) - mean * mean;
        float rstd = rsqrtf(var + 1e-5f);
        s16x8 o0, o1;
        #pragma unroll
        for (int q = 0; q < 4; q++) {
            float vx = (xv[q].x - mean) * rstd * lwv[q].x;
            float vy = (xv[q].y - mean) * rstd * lwv[q].y;
            float vz = (xv[q].z - mean) * rstd * lwv[q].z;
            float vw = (xv[q].w - mean) * rstd * lwv[q].w;
            if (q < 2) {
                o0[q * 4 + 0] = (short)f2bf(vx); o0[q * 4 + 1] = (short)f2bf(vy);
                o0[q * 4 + 2] = (short)f2bf(vz); o0[q * 4 + 3] = (short)f2bf(vw);
            } else {
                o1[(q - 2) * 4 + 0] = (short)f2bf(vx); o1[(q - 2) * 4 + 1] = (short)f2bf(vy);
                o1[(q - 2) * 4 + 2] = (short)f2bf(vz); o1[(q - 2) * 4 + 3] = (short)f2bf(vw);
            }
        }
        *reinterpret_cast<s16x8*>(&A_s[r][l15 * 16])     = o0;
        *reinterpret_cast<s16x8*>(&A_s[r][l15 * 16 + 8]) = o1;
    }
    __syncthreads();

    // ---- gated GEMM pass: u = X@Bu, v = X@Bv + bias; out = sig(u)*v [*mask] ----
    auto gated = [&](const unsigned short* Bu, const unsigned short* Bv,
                     const float* bias, unsigned short* outT) {
        f32x4 au[2][4] = {};
        f32x4 av[2][4] = {};
        for (int kk = 0; kk < Ev; kk += 32) {
            const int kc8 = kk >> 5;
            s16x8 a[2], bu[4], bv[4];
            #pragma unroll
            for (int fi = 0; fi < 2; fi++)
                a[fi] = *reinterpret_cast<const s16x8*>(&A_s[wy * 32 + fi * 16 + l15][kk + lg * 8]);
            #pragma unroll
            for (int fj = 0; fj < 4; fj++) {
                size_t fo = (((size_t)(wx * 4 + fj) * 8 + kc8) * 64 + lane) * 8;
                bu[fj] = *reinterpret_cast<const s16x8*>(Bu + fo);
                bv[fj] = *reinterpret_cast<const s16x8*>(Bv + fo);
            }
            #pragma unroll
            for (int fi = 0; fi < 2; fi++)
                #pragma unroll
                for (int fj = 0; fj < 4; fj++) {
                    au[fi][fj] = mfma16(a[fi], bu[fj], au[fi][fj]);
                    av[fi][fj] = mfma16(a[fi], bv[fj], av[fi][fj]);
                }
        }
        __syncthreads();   // all waves done reading A_s (T_s may overlay it)
        #pragma unroll
        for (int fi = 0; fi < 2; fi++)
            #pragma unroll
            for (int r = 0; r < 4; r++) {
                int ml = wy * 32 + fi * 16 + lg * 4 + r;
                float mval = HASMASK ? mask[m0 + ml] : 1.0f;
                #pragma unroll
                for (int fj = 0; fj < 4; fj++) {
                    int c = wx * 64 + fj * 16 + l15;
                    float val = sigmoidf_(au[fi][fj][r]) * (av[fi][fj][r] + bias[c]);
                    T_s[c][ml] = f2bf(val * mval);
                }
            }
        __syncthreads();
        #pragma unroll
        for (int it = 0; it < 4; it++) {
            int cid = it * 256 + t; int c = cid >> 3, ch = cid & 7;
            *reinterpret_cast<float4*>(outT + (size_t)c * M + m0 + ch * 8) =
                *reinterpret_cast<const float4*>(&T_s[c][ch * 8]);
        }
        __syncthreads();
    };

    gated(Bu1, Bv1, bias1, out1);
    if (HAS2) gated(Bu2, Bv2, bias2, out2);

    if (HASG) {
        unsigned short (*T2g)[144] = reinterpret_cast<unsigned short(*)[144]>(
                                         smem + (HAS2 ? 33792 : 0));
        #pragma unroll
        for (int half = 0; half < 2; half++) {
            f32x4 au[2][4] = {};
            for (int kk = 0; kk < Ev; kk += 32) {
                const int kc8 = kk >> 5;
                s16x8 a[2], bu[4];
                #pragma unroll
                for (int fi = 0; fi < 2; fi++)
                    a[fi] = *reinterpret_cast<const s16x8*>(&A_s[wy * 32 + fi * 16 + l15][kk + lg * 8]);
                #pragma unroll
                for (int fj = 0; fj < 4; fj++) {
                    size_t fo = (((size_t)(half * 8 + wx * 4 + fj) * 8 + kc8) * 64 + lane) * 8;
                    bu[fj] = *reinterpret_cast<const s16x8*>(Bwe + fo);
                }
                #pragma unroll
                for (int fi = 0; fi < 2; fi++)
                    #pragma unroll
                    for (int fj = 0; fj < 4; fj++)
                        au[fi][fj] = mfma16(a[fi], bu[fj], au[fi][fj]);
            }
            __syncthreads();   // T2g overlays T_s; previous reads must complete
            #pragma unroll
            for (int fi = 0; fi < 2; fi++)
                #pragma unroll
                for (int fj = 0; fj < 4; fj++) {
                    int np = wx * 64 + fj * 16 + l15;
                    float bev = be[half * 128 + np];
                    #pragma unroll
                    for (int r = 0; r < 4; r++) {
                        int ml = wy * 32 + fi * 16 + lg * 4 + r;
                        T2g[ml][np] = f2bf(sigmoidf_(au[fi][fj][r] + bev));
                    }
                }
            __syncthreads();
            #pragma unroll
            for (int it = 0; it < 4; it++) {
                int cid = it * 256 + t; int m = cid >> 4, ch = cid & 15;
                *reinterpret_cast<float4*>(gout + (size_t)(m0 + m) * Ev + half * 128 + ch * 8) =
                    *reinterpret_cast<const float4*>(&T2g[m][ch * 8]);
            }
            __syncthreads();
        }
    }
}

// ---------------------------------------------------------------------------
// ab1 transpose: [c][ip 512][jc 128] -> [c][jc 128][ip 512]
// ---------------------------------------------------------------------------
__global__ void transpose_ab1(const unsigned short* __restrict__ in,
                              unsigned short* __restrict__ out)
{
    __shared__ unsigned short T[64][72];
    const int t = threadIdx.x;
    const int c   = blockIdx.z;
    const int ip0 = blockIdx.x * 64;
    const int jc0 = blockIdx.y * 64;
    const unsigned short* src = in  + (size_t)c * (NPv * NCv);
    unsigned short*       dst = out + (size_t)c * (NPv * NCv);
    #pragma unroll
    for (int it = 0; it < 2; it++) {
        int cid = it * 256 + t; int r = cid >> 3, ch = cid & 7;
        *reinterpret_cast<float4*>(&T[r][ch * 8]) =
            *reinterpret_cast<const float4*>(src + (size_t)(ip0 + r) * NCv + jc0 + ch * 8);
    }
    __syncthreads();
    #pragma unroll
    for (int it = 0; it < 2; it++) {
        int cid = it * 256 + t; int jr = cid >> 3, ch = cid & 7;
        unsigned short v[8];
        #pragma unroll
        for (int e = 0; e < 8; e++) v[e] = T[ch * 8 + e][jr];
        *reinterpret_cast<float4*>(dst + (size_t)(jc0 + jr) * NPv + ip0 + ch * 8) =
            *reinterpret_cast<const float4*>(v);
    }
}

// ---------------------------------------------------------------------------
// block1 + block2 fused, per channel c: acc[i][j] = sum_k pp[c][i][k]*ab1tt[c][j][k]
//                                             + sum_k2 ab2t[c][i][k2]*cpt[c][j][k2]
// ---------------------------------------------------------------------------
__global__ __launch_bounds__(256, 2)
void block_kernel(const unsigned short* __restrict__ ppt,
                  const unsigned short* __restrict__ ab1tt,
                  const unsigned short* __restrict__ ab2t,
                  const unsigned short* __restrict__ cpt,
                  float* __restrict__ blockT)
{
    __shared__ unsigned short A_s[128][40];
    __shared__ unsigned short B_s[128][40];
    const int t = threadIdx.x, lane = t & 63, w = t >> 6;
    const int l15 = lane & 15, lg = lane >> 4;
    const int c  = blockIdx.x;
    const int i0 = blockIdx.y * 128;
    const int wy = w >> 1, wx = w & 1;
    f32x4 acc[4][4] = {};

    const unsigned short* pa = ppt   + (size_t)c * (NPv * NPv);  // [i][k] K=512
    const unsigned short* pb = ab1tt + (size_t)c * (NCv * NPv);  // [j][k] K=512
    for (int kk = 0; kk < NPv; kk += 32) {
        __syncthreads();
        #pragma unroll
        for (int it = 0; it < 2; it++) {
            int cid = it * 256 + t; int r = cid >> 2, ch = cid & 3;
            *reinterpret_cast<float4*>(&A_s[r][ch * 8]) =
                *reinterpret_cast<const float4*>(pa + (size_t)(i0 + r) * NPv + kk + ch * 8);
            *reinterpret_cast<float4*>(&B_s[r][ch * 8]) =
                *reinterpret_cast<const float4*>(pb + (size_t)r * NPv + kk + ch * 8);
        }
        __syncthreads();
        s16x8 a[4], b[4];
        #pragma unroll
        for (int f = 0; f < 4; f++) {
            a[f] = *reinterpret_cast<const s16x8*>(&A_s[wy * 64 + f * 16 + l15][lg * 8]);
            b[f] = *reinterpret_cast<const s16x8*>(&B_s[wx * 64 + f * 16 + l15][lg * 8]);
        }
        #pragma unroll
        for (int fi = 0; fi < 4; fi++)
            #pragma unroll
            for (int fj = 0; fj < 4; fj++)
                acc[fi][fj] = mfma16(a[fi], b[fj], acc[fi][fj]);
    }

    const unsigned short* pa2 = ab2t + (size_t)c * (NPv * NCv);  // [i][k2] K=128
    const unsigned short* pb2 = cpt  + (size_t)c * (NCv * NCv);  // [j][k2] K=128
    for (int kk = 0; kk < NCv; kk += 32) {
        __syncthreads();
        #pragma unroll
        for (int it = 0; it < 2; it++) {
            int cid = it * 256 + t; int r = cid >> 2, ch = cid & 3;
            *reinterpret_cast<float4*>(&A_s[r][ch * 8]) =
                *reinterpret_cast<const float4*>(pa2 + (size_t)(i0 + r) * NCv + kk + ch * 8);
            *reinterpret_cast<float4*>(&B_s[r][ch * 8]) =
                *reinterpret_cast<const float4*>(pb2 + (size_t)r * NCv + kk + ch * 8);
        }
        __syncthreads();
        s16x8 a[4], b[4];
        #pragma unroll
        for (int f = 0; f < 4; f++) {
            a[f] = *reinterpret_cast<const s16x8*>(&A_s[wy * 64 + f * 16 + l15][lg * 8]);
            b[f] = *reinterpret_cast<const s16x8*>(&B_s[wx * 64 + f * 16 + l15][lg * 8]);
        }
        #pragma unroll
        for (int fi = 0; fi < 4; fi++)
            #pragma unroll
            for (int fj = 0; fj < 4; fj++)
                acc[fi][fj] = mfma16(a[fi], b[fj], acc[fi][fj]);
    }

    float* dst = blockT + (size_t)c * (NPv * NCv);
    #pragma unroll
    for (int fi = 0; fi < 4; fi++)
        #pragma unroll
        for (int fj = 0; fj < 4; fj++) {
            int jc = wx * 64 + fj * 16 + l15;
            #pragma unroll
            for (int r = 0; r < 4; r++) {
                int il = wy * 64 + fi * 16 + lg * 4 + r;
                dst[(size_t)(i0 + il) * NCv + jc] = acc[fi][fj][r];
            }
        }
}

// ---------------------------------------------------------------------------
// Final: LN over c=128 of block (read from blockT[c][m]) -> @ws + bs, * g * mask
// wst is frag-major (KC=4, NB=16).
// ---------------------------------------------------------------------------
__global__ __launch_bounds__(256, 2)
void final_kernel(const float* __restrict__ blockT,
                  const unsigned short* __restrict__ gbuf,
                  const unsigned short* __restrict__ wst,
                  const float* __restrict__ lncw,
                  const float* __restrict__ bs,
                  const float* __restrict__ mask,
                  float* __restrict__ out)
{
    __shared__ float Bl[128][68];
    __shared__ unsigned short A_s[64][136];
    __shared__ float red[8][64];
    const int t = threadIdx.x, lane = t & 63, w = t >> 6;
    const int l15 = lane & 15, lg = lane >> 4;
    const int m0 = blockIdx.x * 64;

    #pragma unroll
    for (int it = 0; it < 8; it++) {
        int cid = it * 256 + t; int c = cid >> 4, ch = cid & 15;
        *reinterpret_cast<float4*>(&Bl[c][ch * 4]) =
            *reinterpret_cast<const float4*>(blockT + (size_t)c * 65536 + m0 + ch * 4);
    }
    __syncthreads();

    const int m = t & 63, part = t >> 6;
    float s = 0.f, s2 = 0.f;
    for (int c = part * 32; c < part * 32 + 32; c++) { float v = Bl[c][m]; s += v; s2 += v * v; }
    red[part][m] = s; red[4 + part][m] = s2;
    __syncthreads();
    float ss  = red[0][m] + red[1][m] + red[2][m] + red[3][m];
    float ss2 = red[4][m] + red[5][m] + red[6][m] + red[7][m];
    float mean = ss * (1.0f / 128.0f);
    float var  = ss2 * (1.0f / 128.0f) - mean * mean;
    float rstd = rsqrtf(var + 1e-5f);
    for (int c = part * 32; c < part * 32 + 32; c++)
        A_s[m][c] = f2bf((Bl[c][m] - mean) * rstd * lncw[c]);
    __syncthreads();

    const int wy = w >> 1, wx = w & 1;
    f32x4 acc[2][8] = {};
    for (int kk = 0; kk < 128; kk += 32) {
        const int kc4 = kk >> 5;
        s16x8 a[2], b[8];
        #pragma unroll
        for (int fi = 0; fi < 2; fi++)
            a[fi] = *reinterpret_cast<const s16x8*>(&A_s[wy * 32 + fi * 16 + l15][kk + lg * 8]);
        #pragma unroll
        for (int fj = 0; fj < 8; fj++) {
            size_t fo = (((size_t)(wx * 8 + fj) * 4 + kc4) * 64 + lane) * 8;
            b[fj] = *reinterpret_cast<const s16x8*>(wst + fo);
        }
        #pragma unroll
        for (int fi = 0; fi < 2; fi++)
            #pragma unroll
            for (int fj = 0; fj < 8; fj++)
                acc[fi][fj] = mfma16(a[fi], b[fj], acc[fi][fj]);
    }
    #pragma unroll
    for (int fi = 0; fi < 2; fi++)
        #pragma unroll
        for (int fj = 0; fj < 8; fj++) {
            int n = wx * 128 + fj * 16 + l15;
            float bsn = bs[n];
            #pragma unroll
            for (int r = 0; r < 4; r++) {
                int ml = wy * 32 + fi * 16 + lg * 4 + r;
                float gval = bf2f(gbuf[(size_t)(m0 + ml) * Ev + n]);
                out[(size_t)(m0 + ml) * Ev + n] =
                    gval * (acc[fi][fj][r] + bsn) * mask[m0 + ml];
            }
        }
}

// ---------------------------------------------------------------------------
extern "C" void kernel_launch(void* const* d_in, const int* in_sizes, int n_in,
                              void* d_out, int out_size, void* d_ws, size_t ws_size,
                              hipStream_t stream)
{
    const float* z    = (const float*)d_in[0];
    const float* ppin = (const float*)d_in[1];
    const float* cpin = (const float*)d_in[2];
    const float* mask = (const float*)d_in[3];
    const float* lnw  = (const float*)d_in[4];
    const float* lncw = (const float*)d_in[5];
    const float* gw1  = (const float*)d_in[6];
    const float* gw2  = (const float*)d_in[7];
    const float* w1   = (const float*)d_in[8];
    const float* b1   = (const float*)d_in[9];
    const float* w2   = (const float*)d_in[10];
    const float* b2   = (const float*)d_in[11];
    const float* we   = (const float*)d_in[12];
    const float* be   = (const float*)d_in[13];
    const float* wsm  = (const float*)d_in[14];
    const float* bs   = (const float*)d_in[15];
    float* out = (float*)d_out;

    char* p = (char*)d_ws;
    auto alloc = [&](size_t bytes) { char* r = p; p += (bytes + 255) & ~(size_t)255; return r; };
    unsigned short* wts    = (unsigned short*)alloc((size_t)229376 * 2);
    unsigned short* abt1   = (unsigned short*)alloc((size_t)128 * 65536 * 2);
    unsigned short* ab2t   = (unsigned short*)alloc((size_t)128 * 65536 * 2);
    unsigned short* ab1tt  = (unsigned short*)alloc((size_t)128 * 65536 * 2);
    unsigned short* pptb   = (unsigned short*)alloc((size_t)128 * 262144 * 2);
    unsigned short* cptb   = (unsigned short*)alloc((size_t)128 * 16384 * 2);
    unsigned short* gbuf   = (unsigned short*)alloc((size_t)65536 * 256 * 2);
    float*          blockT = (float*)alloc((size_t)128 * 65536 * 4);

    unsigned short* gw1t = wts + 0;
    unsigned short* w1t  = wts + 32768;
    unsigned short* gw2t = wts + 65536;
    unsigned short* w2t  = wts + 98304;
    unsigned short* wet  = wts + 131072;
    unsigned short* wst  = wts + 196608;

    hipLaunchKernelGGL(prep_weights, dim3(896), dim3(256), 0, stream,
                       gw1, w1, gw2, w2, we, wsm, wts);
    hipLaunchKernelGGL((ln_gate_kernel<1, 1, 1>), dim3(1024), dim3(256), 0, stream,
                       z, 65536, lnw, gw1t, w1t, b1, abt1, gw2t, w2t, b2, ab2t,
                       wet, be, gbuf, mask);
    hipLaunchKernelGGL((ln_gate_kernel<0, 0, 0>), dim3(4096), dim3(256), 0, stream,
                       ppin, 262144, lnw, gw2t, w2t, b2, pptb,
                       (const unsigned short*)nullptr, (const unsigned short*)nullptr,
                       (const float*)nullptr, (unsigned short*)nullptr,
                       (const unsigned short*)nullptr, (const float*)nullptr,
                       (unsigned short*)nullptr, (const float*)nullptr);
    hipLaunchKernelGGL((ln_gate_kernel<0, 0, 0>), dim3(256), dim3(256), 0, stream,
                       cpin, 16384, lnw, gw1t, w1t, b1, cptb,
                       (const unsigned short*)nullptr, (const unsigned short*)nullptr,
                       (const float*)nullptr, (unsigned short*)nullptr,
                       (const unsigned short*)nullptr, (const float*)nullptr,
                       (unsigned short*)nullptr, (const float*)nullptr);
    hipLaunchKernelGGL(transpose_ab1, dim3(8, 2, 128), dim3(256), 0, stream, abt1, ab1tt);
    hipLaunchKernelGGL(block_kernel, dim3(128, 4), dim3(256), 0, stream,
                       pptb, ab1tt, ab2t, cptb, blockT);
    hipLaunchKernelGGL(final_kernel, dim3(1024), dim3(256), 0, stream,
                       blockT, gbuf, wst, lncw, bs, mask, out);
}